// Round 1
// baseline (61.305 us; speedup 1.0000x reference)
//
#include <hip/hip_runtime.h>
#include <math.h>

// Problem constants (match reference): B=8, N=256, MAX_DIM=2, D=4
#define PB 8
#define PN 256
#define PD 4
#define PEPS 1e-8f

// Kernel 1: one block per (dim, batch). Computes masked projections for
// set1/set2, bitonic-sorts both 256-element arrays in LDS, and reduces
// sum |sorted_p1 - sorted_p2| -> partial[block].
//
// Why sorting is valid: the Hungarian assignment on cost |a_i - b_j| over
// scalars attains its (unique) minimum cost by matching in sorted order;
// the reference only uses the total cost, never the permutation itself.
__global__ __launch_bounds__(256) void hung_partial_kernel(
    const float* __restrict__ set1,   // [B, N, D] fp32
    const float* __restrict__ set2,   // [B, N, D] fp32
    float* __restrict__ partial)      // [16] fp32
{
    const int blk = blockIdx.x;       // 0..15
    const int dim = blk >> 3;         // 0 or 1
    const int b   = blk & 7;          // 0..7
    const int tid = threadIdx.x;      // 0..255

    __shared__ float s1[PN];
    __shared__ float s2[PN];

    // ---- load this thread's point from each set ----
    const float* e1 = set1 + ((size_t)b * PN + tid) * PD;
    const float* e2 = set2 + ((size_t)b * PN + tid) * PD;
    float x1 = e1[0], y1 = e1[1], l1 = e1[2];
    float x2 = e2[0], y2 = e2[1], a2 = e2[2], b2 = e2[3];

    // set1 mask: stored float label == dim (labels are exact 0.0/1.0)
    bool m1 = (l1 == (float)dim);
    // set2 mask: argmax over last-2 cols, first-index tie-break
    int lab2 = (b2 > a2) ? 1 : 0;
    bool m2 = (lab2 == dim);

    // masked coords (reference multiplies whole point by mask -> exact 0)
    float mx1 = m1 ? x1 : 0.0f, my1 = m1 ? y1 : 0.0f;
    float mx2 = m2 ? x2 : 0.0f, my2 = m2 ? y2 : 0.0f;

    // projection: x + sqrt(y + eps)/2  (both halves get y zeroed in ref)
    s1[tid] = mx1 + sqrtf(my1 + PEPS) * 0.5f;
    s2[tid] = mx2 + sqrtf(my2 + PEPS) * 0.5f;
    __syncthreads();

    // ---- bitonic sort both arrays (256 elems, 256 threads) ----
    for (int k = 2; k <= PN; k <<= 1) {
        for (int j = k >> 1; j > 0; j >>= 1) {
            int ixj = tid ^ j;
            if (ixj > tid) {
                bool up = ((tid & k) == 0);
                float a = s1[tid], bb = s1[ixj];
                if ((a > bb) == up) { s1[tid] = bb; s1[ixj] = a; }
                float c = s2[tid], dd = s2[ixj];
                if ((c > dd) == up) { s2[tid] = dd; s2[ixj] = c; }
            }
            __syncthreads();
        }
    }

    // ---- reduce sum |s1 - s2| across the block ----
    float v = fabsf(s1[tid] - s2[tid]);
    #pragma unroll
    for (int off = 32; off > 0; off >>= 1)
        v += __shfl_down(v, off, 64);   // wave = 64 lanes on CDNA

    __shared__ float wsum[4];
    int lane = tid & 63, wid = tid >> 6;
    if (lane == 0) wsum[wid] = v;
    __syncthreads();
    if (tid == 0)
        partial[blk] = wsum[0] + wsum[1] + wsum[2] + wsum[3];
}

// Kernel 2: fold 16 partials into the scalar output.
// total = sum_{dim,b} cost * 2 (concat symmetry) / N (mean over rows)
__global__ void hung_final_kernel(const float* __restrict__ partial,
                                  float* __restrict__ out)
{
    if (threadIdx.x == 0) {
        float s = 0.0f;
        #pragma unroll
        for (int i = 0; i < 16; ++i) s += partial[i];
        out[0] = s * (2.0f / (float)PN);
    }
}

extern "C" void kernel_launch(void* const* d_in, const int* in_sizes, int n_in,
                              void* d_out, int out_size, void* d_ws, size_t ws_size,
                              hipStream_t stream) {
    const float* set1 = (const float*)d_in[0];   // [B,N,D] fp32
    const float* set2 = (const float*)d_in[1];   // [B,N,D] fp32
    float* partial = (float*)d_ws;               // 16 floats scratch
    float* out = (float*)d_out;                  // 1 float

    hung_partial_kernel<<<16, 256, 0, stream>>>(set1, set2, partial);
    hung_final_kernel<<<1, 64, 0, stream>>>(partial, out);
}